// Round 8
// baseline (546.234 us; speedup 1.0000x reference)
//
#include <hip/hip_runtime.h>
#include <hip/hip_bf16.h>

// Problem: N=4,C=64,F=100,T=200,H=16 ; B=N*F=400, BT=80000
// r8: r7's fused-GEMM k_lstm (507us total, k_lstm 197us) measured 342 VALU
// instr/step (VALUBusy 67.7% x 474k cyc) vs ~120 algorithmic -- the f32x2 /
// hh2 splat machinery bloats codegen 3x (pair movs, op_sel packing, acc
// field packing). Kernel is VALU-ISSUE-bound at 2.34 waves/SIMD, so instr
// count ~= time. This round: scalar gate math. Weights in LDS transposed as
// float4 wl4[k][c]={Wi,Wf,Wg,Wo} -> 16 ds_read_b128 + 64 plain v_fma_f32 +
// 16 DPP + ~30 gate ops per step, no packing. Even/odd-k split keeps FMA
// depth 8. MFMA input-GEMM front-end (8 MFMAs per 4 steps, fp32 pre-acts,
// bias in C-operand, k_xg-proven D mapping) unchanged.
// Pipeline per chunk: ln1 (fp32->bf16 xr/xi) -> k_lstm (fused GEMM+recur) ->
//   attention (mult. causal mask BEFORE softmax, suffix-V) -> combine+LN2+
//   complex linear+LN3+PReLU+residual.
// ws: header 204800 B (bihh fp32 @0, Wih-bf16 @8192), then per chunk:
//   xr bf16 [NB][200][64], xi same, h f32 [24][NB][200][16],
//   att f32 [8][NB][200][16].  Total = 204800 + NB*460800.

typedef __attribute__((ext_vector_type(8))) short bf16x8;
typedef __attribute__((ext_vector_type(4))) float f32x4;

static __device__ __forceinline__ float bf2f(unsigned short u) {
  return __uint_as_float(((unsigned)u) << 16);
}
static __device__ __forceinline__ unsigned short f2bfu(float x) {
  __hip_bfloat16 h = __float2bfloat16(x);
  return *(unsigned short*)&h;
}
static __device__ __forceinline__ float sigf(float x) {
  return __fdividef(1.f, 1.f + __expf(-x));
}
static __device__ __forceinline__ float tanh_(float x) {
  return 1.f - __fdividef(2.f, __expf(2.f * x) + 1.f);  // safe at +-inf
}

// Broadcast lane (row-base + I) of h to all 16 lanes of its row.
// ROW_NEWBCAST:I = dpp_ctrl 0x150+I (CDNA2+/gfx950). Bit-exact equal to
// __shfl(h, (lane&48)+I, 64) since chains occupy aligned 16-lane rows.
template <int CTRL>
static __device__ __forceinline__ float dpp_bcast(float x) {
  int xi = __float_as_int(x);
  int r = __builtin_amdgcn_update_dpp(xi, xi, CTRL, 0xF, 0xF, false);
  return __int_as_float(r);
}

// ---------------- kernel A: LN1 over C -> xr/xi bf16 [bl][t][c]
__global__ __launch_bounds__(256) void k_ln1(const float* __restrict__ in,
    const float* __restrict__ w, const float* __restrict__ bsh,
    unsigned short* __restrict__ xr, unsigned short* __restrict__ xi, int b0) {
  __shared__ float is[64][101];   // [c][(tloc,ri)]
  __shared__ float os[100][65];   // [(tloc,ri)][c]
  int bid = blockIdx.x;
  int nfl = bid >> 2, tile = bid & 3;         // NB nf-local x 4 tiles of 50 t
  int nf = b0 + nfl;
  int t0 = tile * 50;
  int n = nf / 100, f = nf - n * 100;
  int tid = threadIdx.x;
  for (int i = 0; i < 7; ++i) {               // 64 rows x 25 float4
    int idx = tid + i * 256;
    if (idx < 1600) {
      int c = idx / 25, q = idx - c * 25;
      float4 v = *(const float4*)(in + (size_t)((n * 64 + c) * 100 + f) * 400
                                  + t0 * 2 + q * 4);
      is[c][q*4+0] = v.x; is[c][q*4+1] = v.y; is[c][q*4+2] = v.z; is[c][q*4+3] = v.w;
    }
  }
  __syncthreads();
  if (tid < 100) {
    float s = 0.f, ss = 0.f;
    #pragma unroll
    for (int c = 0; c < 64; ++c) { float v = is[c][tid]; s += v; ss += v * v; }
    float mean = s * 0.015625f;
    float var  = ss * 0.015625f - mean * mean;
    float rstd = rsqrtf(var + 1e-5f);
    #pragma unroll
    for (int c = 0; c < 64; ++c)
      os[tid][c] = (is[c][tid] - mean) * rstd * w[c] + bsh[c];
  }
  __syncthreads();
  for (int ri = 0; ri < 2; ++ri) {
    unsigned short* dst = ri ? xi : xr;
    for (int i = 0; i < 4; ++i) {             // 50 rows x 16 ushort4 per ri
      int idx = tid + i * 256;
      if (idx < 800) {
        int t = idx >> 4, q = idx & 15;
        ushort4 v;
        v.x = f2bfu(os[t*2+ri][q*4+0]); v.y = f2bfu(os[t*2+ri][q*4+1]);
        v.z = f2bfu(os[t*2+ri][q*4+2]); v.w = f2bfu(os[t*2+ri][q*4+3]);
        *(ushort4*)(dst + ((size_t)nfl * 200 + t0 + t) * 64 + q * 4) = v;
      }
    }
  }
}

// ---------------- prep: bihh = bih + bhh ; wbf = bf16(Wih)
__global__ void k_prep(const float* __restrict__ bih, const float* __restrict__ bhh,
                       const float* __restrict__ Wih, float* __restrict__ bihh,
                       unsigned short* __restrict__ wbf) {
  int i = blockIdx.x * 256 + threadIdx.x;
  if (i < 1536) bihh[i] = bih[i] + bhh[i];
  if (i < 98304) wbf[i] = f2bfu(Wih[i]);
}

// ---------------- kernel R: fused input-GEMM + LSTM recurrence.
// 1 wave = 4 chains of the SAME l (grid 24 x ceil(NB/4); dup chains clamp to
// b=NB-1, identical writes). lane = (q=lane>>4 chain, c=lane&15 unit).
// Every 4 steps, MGROUP computes pre-acts via 8 MFMAs:
//   A rows m = b_local*4+dt of x_sel (bf16), B = Wih[l] rows jt*16+c,
//   C = bias splat. D mapping (col=lane&15=unit c, row=q*4+r -> chain q,
//   dt=r) lands each value in its consumer lane. One group pipelined ahead.
// Recurrence matvec: SCALAR. Whh[l] transposed in LDS as
//   float4 wl4[k][c] = {W[c][k], W[16+c][k], W[32+c][k], W[48+c][k]}
// -> per step: 16 ds_read_b128 (lane c reads its own 16B; 2-way bank alias =
// free; 4 chain-groups broadcast) + 64 v_fma_f32, no f32x2 splat/pack bloat
// (r7 measured 342 VALU/step vs ~120 algorithmic). Even/odd-k accumulator
// split keeps FMA dep depth 8. h-broadcast via DPP row_newbcast.
__global__ __launch_bounds__(64) void k_lstm(const unsigned short* __restrict__ xr,
    const unsigned short* __restrict__ xi, const unsigned short* __restrict__ wbf,
    const float* __restrict__ bihh, const float* __restrict__ Whh,
    float* __restrict__ hbuf, int NB, int nbq) {
  __shared__ float4 wl4[16][16];          // [k][unit] = 4 gate weights
  int lane = threadIdx.x;
  int q = lane >> 4, c = lane & 15;       // chain-in-block, unit
  int lq = blockIdx.x / nbq, q4 = blockIdx.x - lq * nbq;
  int l = lq;
  int b = q4 * 4 + q; if (b >= NB) b = NB - 1;   // dup chains: identical writes
  const float* Wg = Whh + (size_t)l * 1024;
  for (int idx = lane; idx < 256; idx += 64) {   // one-time transpose fill
    int kk = idx >> 4, cc = idx & 15;
    float4 w;
    w.x = Wg[(cc)      * 16 + kk];
    w.y = Wg[(16 + cc) * 16 + kk];
    w.z = Wg[(32 + cc) * 16 + kk];
    w.w = Wg[(48 + cc) * 16 + kk];
    wl4[kk][cc] = w;
  }
  __syncthreads();
  int sel = (0xE54770 >> l) & 1;                 // per-lstm real/imag selection
  const unsigned short* xs = sel ? xi : xr;
  // A-frag source: lane (q,c) holds x row m = c -> b_local=c>>2, dt=c&3.
  int ba = q4 * 4 + (c >> 2); if (ba >= NB) ba = NB - 1;
  const unsigned short* ap2 = xs + ((size_t)ba * 200 + (c & 3)) * 64 + q * 8;
  // B-frag source: Wih row jt*16 + c, channels q*8+e (jt stride 1024 ushorts)
  const unsigned short* wrow = wbf + l * 4096 + c * 64 + q * 8;
  // bias splats (C-operand of first MFMA of each gate)
  float bv0 = bihh[l * 64 + c], bv1 = bihh[l * 64 + 16 + c];
  float bv2 = bihh[l * 64 + 32 + c], bv3 = bihh[l * 64 + 48 + c];
  f32x4 zb0 = {bv0, bv0, bv0, bv0}, zb1 = {bv1, bv1, bv1, bv1};
  f32x4 zb2 = {bv2, bv2, bv2, bv2}, zb3 = {bv3, bv3, bv3, bv3};
  float* hp = hbuf + ((size_t)l * NB + b) * 3200 + c;
  float h = 0.f, cs = 0.f;
  int tcur = 0;
#define MG1(DST, OFS, ZB, A0v, A1v) { \
  bf16x8 w0_ = *(const bf16x8*)(wrow + OFS); \
  bf16x8 w1_ = *(const bf16x8*)(wrow + OFS + 32); \
  f32x4 t_ = __builtin_amdgcn_mfma_f32_16x16x32_bf16(A0v, w0_, ZB, 0, 0, 0); \
  DST = __builtin_amdgcn_mfma_f32_16x16x32_bf16(A1v, w1_, t_, 0, 0, 0); }
#define MGROUP(D0, D1, D2, D3, A0v, A1v) \
  MG1(D0, 0, zb0, A0v, A1v) MG1(D1, 1024, zb1, A0v, A1v) \
  MG1(D2, 2048, zb2, A0v, A1v) MG1(D3, 3072, zb3, A0v, A1v)
#define HV(i) dpp_bcast<0x150 + i>(h)
#define LSTEP2(AC0, AC1, AC2, AC3, FLD) { \
  float hv[16]; \
  hv[0]  = HV(0);  hv[1]  = HV(1);  hv[2]  = HV(2);  hv[3]  = HV(3);  \
  hv[4]  = HV(4);  hv[5]  = HV(5);  hv[6]  = HV(6);  hv[7]  = HV(7);  \
  hv[8]  = HV(8);  hv[9]  = HV(9);  hv[10] = HV(10); hv[11] = HV(11); \
  hv[12] = HV(12); hv[13] = HV(13); hv[14] = HV(14); hv[15] = HV(15); \
  float ai_ = AC0.FLD, af_ = AC1.FLD, ag_ = AC2.FLD, ao_ = AC3.FLD; \
  float bi_ = 0.f, bf_ = 0.f, bg_ = 0.f, bo_ = 0.f; \
  _Pragma("unroll") \
  for (int kk = 0; kk < 16; kk += 2) { \
    float4 wA = wl4[kk][c]; \
    float4 wB = wl4[kk + 1][c]; \
    float hA = hv[kk], hB = hv[kk + 1]; \
    ai_ += wA.x * hA; af_ += wA.y * hA; ag_ += wA.z * hA; ao_ += wA.w * hA; \
    bi_ += wB.x * hB; bf_ += wB.y * hB; bg_ += wB.z * hB; bo_ += wB.w * hB; \
  } \
  ai_ += bi_; af_ += bf_; ag_ += bg_; ao_ += bo_; \
  float ig_ = sigf(ai_), fg_ = sigf(af_); \
  float gg_ = tanh_(ag_), og_ = sigf(ao_); \
  cs = fg_ * cs + ig_ * gg_; \
  h = og_ * tanh_(cs); \
  hp[tcur * 16] = h; ++tcur; }
  // prologue: group 0 pre-acts; prefetch A of group 1
  bf16x8 a0 = *(const bf16x8*)(ap2), a1 = *(const bf16x8*)(ap2 + 32);
  f32x4 c0, c1, c2, c3, n0, n1, n2, n3;
  MGROUP(c0, c1, c2, c3, a0, a1);
  ap2 += 256;
  a0 = *(const bf16x8*)(ap2); a1 = *(const bf16x8*)(ap2 + 32);
  for (int g = 0; g < 50; ++g) {
    LSTEP2(c0, c1, c2, c3, x)
    LSTEP2(c0, c1, c2, c3, y)
    MGROUP(n0, n1, n2, n3, a0, a1);      // pre-acts for group g+1
    if (g < 48) ap2 += 256;              // A of group g+2 (clamped at end)
    a0 = *(const bf16x8*)(ap2); a1 = *(const bf16x8*)(ap2 + 32);
    LSTEP2(c0, c1, c2, c3, z)
    LSTEP2(c0, c1, c2, c3, w)
    c0 = n0; c1 = n1; c2 = n2; c3 = n3;
  }
#undef LSTEP2
#undef HV
#undef MGROUP
#undef MG1
}

// ---------------- kernel C: attention per (branch, bl). Multiplicative causal
// mask before softmax: masked s get weight exp(0); handled via suffix-V init.
__global__ __launch_bounds__(256) void k_attn(const float* __restrict__ hbuf,
                                              float* __restrict__ att, int NB) {
  __shared__ float Q[200][17];
  __shared__ float K[200][16];
  __shared__ float V[200][16];
  __shared__ float Vs[200][17];
  int bid = blockIdx.x;                 // 8 br x NB
  int br = bid / NB, b = bid - br * NB;
  int tid = threadIdx.x;
  const float* qg = hbuf + ((size_t)(br * 3 + 0) * NB + b) * 3200;
  const float* kg = hbuf + ((size_t)(br * 3 + 1) * NB + b) * 3200;
  const float* vg = hbuf + ((size_t)(br * 3 + 2) * NB + b) * 3200;
  for (int i = 0; i < 4; ++i) {         // 200 rows x 4 f4 each of Q,K,V
    int idx = tid + i * 256;
    if (idx < 800) {
      int t = idx >> 2, q = idx & 3;
      float4 a = *(const float4*)(qg + t * 16 + q * 4);
      Q[t][q*4+0] = a.x; Q[t][q*4+1] = a.y; Q[t][q*4+2] = a.z; Q[t][q*4+3] = a.w;
      *(float4*)&K[t][q * 4] = *(const float4*)(kg + t * 16 + q * 4);
      *(float4*)&V[t][q * 4] = *(const float4*)(vg + t * 16 + q * 4);
    }
  }
  __syncthreads();
  if (tid < 16) {                       // suffix sums of V
    float acc = 0.f;
    Vs[199][tid] = 0.f;
    for (int t = 198; t >= 0; --t) { acc += V[t + 1][tid]; Vs[t][tid] = acc; }
  }
  __syncthreads();
  if (tid < 200) {
    int t = tid;
    float q0[16], va[16];
    #pragma unroll
    for (int k = 0; k < 16; ++k) q0[k] = Q[t][k] * 0.25f;   // fold /sqrt(16)
    #pragma unroll
    for (int k = 0; k < 16; ++k) va[k] = Vs[t][k];          // masked: weight exp(0)=1
    float S = (float)(199 - t);
    for (int s = 0; s <= t; ++s) {
      float e = 0.f;
      #pragma unroll
      for (int k = 0; k < 16; ++k) e += q0[k] * K[s][k];
      float wgt = __expf(e);
      S += wgt;
      #pragma unroll
      for (int k = 0; k < 16; ++k) va[k] += wgt * V[s][k];
    }
    float inv = __fdividef(1.f, S);
    float* dst = att + (((size_t)br * NB + b) * 200 + t) * 16;
    #pragma unroll
    for (int q = 0; q < 4; ++q) {
      float4 v; v.x = va[q*4+0]*inv; v.y = va[q*4+1]*inv;
      v.z = va[q*4+2]*inv; v.w = va[q*4+3]*inv;
      *(float4*)(dst + q * 4) = v;
    }
  }
}

// ---------------- kernel D: combine branches + LN2 + complex linear + LN3 +
// PReLU + residual, with LDS transpose for coalesced [N,C,F,T,2] IO.
__global__ __launch_bounds__(256) void k_out(const float* __restrict__ att,
    const float* __restrict__ in,
    const float* __restrict__ ln2w, const float* __restrict__ ln2b,
    const float* __restrict__ lrw, const float* __restrict__ lrb,
    const float* __restrict__ liw, const float* __restrict__ lib,
    const float* __restrict__ ln3w, const float* __restrict__ ln3b,
    const float* __restrict__ pa, float* __restrict__ out, int b0, int NB) {
  __shared__ float as_[8][40][17];
  __shared__ float ys[40][2][17];
  __shared__ float zs[64][81];
  int bid = blockIdx.x;                 // NB nf-local x 5 tiles of 40 t
  int nfl = bid / 5, tile = bid - nfl * 5;
  int nf = b0 + nfl;
  int t0 = tile * 40;
  int n = nf / 100, f = nf - n * 100;
  int tid = threadIdx.x;
  for (int i = 0; i < 5; ++i) {         // att: 8 br x 40 t x 4 f4
    int idx = tid + i * 256;
    int br = idx / 160, r = idx - br * 160;
    int t = r >> 2, q = r & 3;
    float4 v = *(const float4*)(att + (((size_t)br * NB + nfl) * 200 + t0 + t) * 16 + q * 4);
    as_[br][t][q*4+0] = v.x; as_[br][t][q*4+1] = v.y;
    as_[br][t][q*4+2] = v.z; as_[br][t][q*4+3] = v.w;
  }
  __syncthreads();
  if (tid < 80) {                       // combine + LN2 per (t,ri)
    int t = tid >> 1, ri = tid & 1;
    float vv[16]; float s = 0.f, ss = 0.f;
    #pragma unroll
    for (int k = 0; k < 16; ++k) {
      float v;
      if (ri == 0) v = as_[0][t][k] - as_[1][t][k] - as_[2][t][k] - as_[3][t][k];
      else         v = as_[4][t][k] + as_[5][t][k] + as_[6][t][k] - as_[7][t][k];
      vv[k] = v; s += v; ss += v * v;
    }
    float mean = s * 0.0625f;
    float var  = ss * 0.0625f - mean * mean;
    float rstd = rsqrtf(var + 1e-5f);
    #pragma unroll
    for (int k = 0; k < 16; ++k)
      ys[t][ri][k] = (vv[k] - mean) * rstd * ln2w[k] + ln2b[k];
  }
  __syncthreads();
  // complex linear 16->64 + LN3 over c (wave = 64 lanes = c) + PReLU
  int wv = tid >> 6, cc = tid & 63;
  float lr[16], li[16];
  #pragma unroll
  for (int q = 0; q < 4; ++q) {
    float4 v = *(const float4*)(lrw + cc * 16 + q * 4);
    lr[q*4+0] = v.x; lr[q*4+1] = v.y; lr[q*4+2] = v.z; lr[q*4+3] = v.w;
    float4 u = *(const float4*)(liw + cc * 16 + q * 4);
    li[q*4+0] = u.x; li[q*4+1] = u.y; li[q*4+2] = u.z; li[q*4+3] = u.w;
  }
  float brc = lrb[cc], bic = lib[cc];
  float w3 = ln3w[cc], b3 = ln3b[cc];
  float aP = pa[0];
  for (int tt = wv; tt < 40; tt += 4) {
    float zr = brc - bic, zi = brc + bic;
    #pragma unroll
    for (int k = 0; k < 16; ++k) {
      float yr = ys[tt][0][k], yi = ys[tt][1][k];
      zr += yr * lr[k] - yi * li[k];
      zi += yi * lr[k] + yr * li[k];
    }
    float s1 = zr, s2 = zr * zr, s3 = zi, s4 = zi * zi;
    #pragma unroll
    for (int m = 1; m < 64; m <<= 1) {
      s1 += __shfl_xor(s1, m, 64);
      s2 += __shfl_xor(s2, m, 64);
      s3 += __shfl_xor(s3, m, 64);
      s4 += __shfl_xor(s4, m, 64);
    }
    float mr = s1 * 0.015625f, vr = s2 * 0.015625f - mr * mr;
    float mi = s3 * 0.015625f, vi = s4 * 0.015625f - mi * mi;
    float r1 = (zr - mr) * rsqrtf(vr + 1e-5f) * w3 + b3;
    float r2 = (zi - mi) * rsqrtf(vi + 1e-5f) * w3 + b3;
    r1 = r1 >= 0.f ? r1 : aP * r1;
    r2 = r2 >= 0.f ? r2 : aP * r2;
    zs[cc][tt * 2 + 0] = r1;
    zs[cc][tt * 2 + 1] = r2;
  }
  __syncthreads();
  for (int i = 0; i < 5; ++i) {         // residual + coalesced write
    int idx = tid + i * 256;            // 64 c x 20 f4
    int c = idx / 20, q = idx - c * 20;
    size_t gaddr = (size_t)((n * 64 + c) * 100 + f) * 400 + t0 * 2 + q * 4;
    float4 v = *(const float4*)(in + gaddr);
    float4 z;
    z.x = zs[c][q*4+0] + v.x; z.y = zs[c][q*4+1] + v.y;
    z.z = zs[c][q*4+2] + v.z; z.w = zs[c][q*4+3] + v.w;
    *(float4*)(out + gaddr) = z;
  }
}

extern "C" void kernel_launch(void* const* d_in, const int* in_sizes, int n_in,
                              void* d_out, int out_size, void* d_ws, size_t ws_size,
                              hipStream_t stream) {
  (void)in_sizes; (void)n_in; (void)out_size;
  const float* inputs = (const float*)d_in[0];
  const float* Wih  = (const float*)d_in[1];
  const float* Whh  = (const float*)d_in[2];
  const float* bih  = (const float*)d_in[3];
  const float* bhh  = (const float*)d_in[4];
  const float* ln1w = (const float*)d_in[5];
  const float* ln1b = (const float*)d_in[6];
  const float* ln2w = (const float*)d_in[7];
  const float* ln2b = (const float*)d_in[8];
  const float* lrw  = (const float*)d_in[9];
  const float* lrb  = (const float*)d_in[10];
  const float* liw  = (const float*)d_in[11];
  const float* lib  = (const float*)d_in[12];
  const float* ln3w = (const float*)d_in[13];
  const float* ln3b = (const float*)d_in[14];
  const float* pa   = (const float*)d_in[15];
  float* out = (float*)d_out;
  char* ws = (char*)d_ws;

  // pick largest chunk NB (400,200,100,50,25) whose buffers fit ws_size
  // per-b: xr+xi 51200 + h 307200 + att 102400 = 460800 B (xg is gone)
  int NB = 400;
  while (NB > 25 && 204800ull + (size_t)NB * 460800ull > ws_size) NB /= 2;
  int nch = 400 / NB;

  float* bihh = (float*)(ws + 0);                        // 6 KB
  unsigned short* wbf = (unsigned short*)(ws + 8192);    // 192 KB bf16 Wih
  size_t o_xr = 204800;
  size_t o_xi = o_xr + (size_t)NB * 25600;
  size_t o_h  = o_xi + (size_t)NB * 25600;
  size_t o_at = o_h  + (size_t)NB * 307200;
  unsigned short* xr = (unsigned short*)(ws + o_xr);
  unsigned short* xi = (unsigned short*)(ws + o_xi);
  float* hbuf = (float*)(ws + o_h);
  float* att  = (float*)(ws + o_at);

  k_prep<<<384, 256, 0, stream>>>(bih, bhh, Wih, bihh, wbf);
  int nbq = (NB + 3) >> 2;              // 4-chain groups per l
  for (int ch = 0; ch < nch; ++ch) {
    int b0 = ch * NB;
    k_ln1 <<<NB * 4,   256, 0, stream>>>(inputs, ln1w, ln1b, xr, xi, b0);
    k_lstm<<<24 * nbq,  64, 0, stream>>>(xr, xi, wbf, bihh, Whh, hbuf, NB, nbq);
    k_attn<<<8 * NB,   256, 0, stream>>>(hbuf, att, NB);
    k_out <<<NB * 5,   256, 0, stream>>>(att, inputs, ln2w, ln2b, lrw, lrb,
                                         liw, lib, ln3w, ln3b, pa, out, b0, NB);
  }
}

// Round 9
// 512.461 us; speedup vs baseline: 1.0659x; 1.0659x over previous
//
#include <hip/hip_runtime.h>
#include <hip/hip_bf16.h>

// Problem: N=4,C=64,F=100,T=200,H=16 ; B=N*F=400, BT=80000
// r9: base = r7 (507us total; k_lstm 197us, VGPR 100, occ 14%). r8's scalar
// rewrite regressed (VGPR 172, occ 9%, 361 instr/step vs r7's 343 -- compiler
// replaced splat bloat with array/address bloat). This round pins the FMA
// count with EXPLICIT v_pk_fma_f32 inline asm: 32 pk_fma/step, h broadcast
// via op_sel (even k reads pair.lo: op_sel_hi:[1,0,1]; odd k reads pair.hi:
// op_sel:[0,1,0]), DPP results written directly into f32x2 halves (no splat
// movs). ~90 instr/step vs 343. Accumulation order identical to r7
// (even-k chain + odd-k chain, then add) -> bit-compatible numerics.
// MFMA input-GEMM front-end (8 MFMAs per 4 steps, fp32 pre-acts, bias in
// C-operand, k_xg-proven D mapping) and all other kernels unchanged from r7.
// ws: header 204800 B (bihh fp32 @0, Wih-bf16 @8192), then per chunk:
//   xr bf16 [NB][200][64], xi same, h f32 [24][NB][200][16],
//   att f32 [8][NB][200][16].  Total = 204800 + NB*460800.

typedef __attribute__((ext_vector_type(8))) short bf16x8;
typedef __attribute__((ext_vector_type(4))) float f32x4;
typedef __attribute__((ext_vector_type(2))) float f32x2;

static __device__ __forceinline__ float bf2f(unsigned short u) {
  return __uint_as_float(((unsigned)u) << 16);
}
static __device__ __forceinline__ unsigned short f2bfu(float x) {
  __hip_bfloat16 h = __float2bfloat16(x);
  return *(unsigned short*)&h;
}
static __device__ __forceinline__ float sigf(float x) {
  return __fdividef(1.f, 1.f + __expf(-x));
}
static __device__ __forceinline__ float tanh_(float x) {
  return 1.f - __fdividef(2.f, __expf(2.f * x) + 1.f);  // safe at +-inf
}

// Broadcast lane (row-base + I) of h to all 16 lanes of its row.
// ROW_NEWBCAST:I = dpp_ctrl 0x150+I (CDNA2+/gfx950). Bit-exact equal to
// __shfl(h, (lane&48)+I, 64) since chains occupy aligned 16-lane rows.
template <int CTRL>
static __device__ __forceinline__ float dpp_bcast(float x) {
  int xi = __float_as_int(x);
  int r = __builtin_amdgcn_update_dpp(xi, xi, CTRL, 0xF, 0xF, false);
  return __int_as_float(r);
}

// ---------------- kernel A: LN1 over C -> xr/xi bf16 [bl][t][c]
__global__ __launch_bounds__(256) void k_ln1(const float* __restrict__ in,
    const float* __restrict__ w, const float* __restrict__ bsh,
    unsigned short* __restrict__ xr, unsigned short* __restrict__ xi, int b0) {
  __shared__ float is[64][101];   // [c][(tloc,ri)]
  __shared__ float os[100][65];   // [(tloc,ri)][c]
  int bid = blockIdx.x;
  int nfl = bid >> 2, tile = bid & 3;         // NB nf-local x 4 tiles of 50 t
  int nf = b0 + nfl;
  int t0 = tile * 50;
  int n = nf / 100, f = nf - n * 100;
  int tid = threadIdx.x;
  for (int i = 0; i < 7; ++i) {               // 64 rows x 25 float4
    int idx = tid + i * 256;
    if (idx < 1600) {
      int c = idx / 25, q = idx - c * 25;
      float4 v = *(const float4*)(in + (size_t)((n * 64 + c) * 100 + f) * 400
                                  + t0 * 2 + q * 4);
      is[c][q*4+0] = v.x; is[c][q*4+1] = v.y; is[c][q*4+2] = v.z; is[c][q*4+3] = v.w;
    }
  }
  __syncthreads();
  if (tid < 100) {
    float s = 0.f, ss = 0.f;
    #pragma unroll
    for (int c = 0; c < 64; ++c) { float v = is[c][tid]; s += v; ss += v * v; }
    float mean = s * 0.015625f;
    float var  = ss * 0.015625f - mean * mean;
    float rstd = rsqrtf(var + 1e-5f);
    #pragma unroll
    for (int c = 0; c < 64; ++c)
      os[tid][c] = (is[c][tid] - mean) * rstd * w[c] + bsh[c];
  }
  __syncthreads();
  for (int ri = 0; ri < 2; ++ri) {
    unsigned short* dst = ri ? xi : xr;
    for (int i = 0; i < 4; ++i) {             // 50 rows x 16 ushort4 per ri
      int idx = tid + i * 256;
      if (idx < 800) {
        int t = idx >> 4, q = idx & 15;
        ushort4 v;
        v.x = f2bfu(os[t*2+ri][q*4+0]); v.y = f2bfu(os[t*2+ri][q*4+1]);
        v.z = f2bfu(os[t*2+ri][q*4+2]); v.w = f2bfu(os[t*2+ri][q*4+3]);
        *(ushort4*)(dst + ((size_t)nfl * 200 + t0 + t) * 64 + q * 4) = v;
      }
    }
  }
}

// ---------------- prep: bihh = bih + bhh ; wbf = bf16(Wih)
__global__ void k_prep(const float* __restrict__ bih, const float* __restrict__ bhh,
                       const float* __restrict__ Wih, float* __restrict__ bihh,
                       unsigned short* __restrict__ wbf) {
  int i = blockIdx.x * 256 + threadIdx.x;
  if (i < 1536) bihh[i] = bih[i] + bhh[i];
  if (i < 98304) wbf[i] = f2bfu(Wih[i]);
}

// ---------------- kernel R: fused input-GEMM + LSTM recurrence.
// 1 wave = 4 chains of the SAME l (grid 24 x ceil(NB/4); dup chains clamp to
// b=NB-1, identical writes). lane = (q=lane>>4 chain, c=lane&15 unit).
// Every 4 steps, MGROUP computes pre-acts via 8 MFMAs:
//   A rows m = b_local*4+dt of x_sel (bf16), B = Wih[l] rows jt*16+c,
//   C = bias splat. D mapping (col=lane&15=unit c, row=q*4+r -> chain q,
//   dt=r) lands each value in its consumer lane. One group pipelined ahead.
// Recurrence matvec: explicit v_pk_fma_f32 asm, 32/step. Whh[l] staged in
// LDS f32x2 wl[2][16][17] (conflict-free broadcast, r6). h-broadcast via DPP
// row_newbcast written straight into f32x2 halves; op_sel broadcasts the
// needed half to both pk lanes (even k: lo via op_sel_hi:[1,0,1]; odd k: hi
// via op_sel:[0,1,0]) -- zero splat movs, scalarizer can't touch the asm.
__global__ __launch_bounds__(64) void k_lstm(const unsigned short* __restrict__ xr,
    const unsigned short* __restrict__ xi, const unsigned short* __restrict__ wbf,
    const float* __restrict__ bihh, const float* __restrict__ Whh,
    float* __restrict__ hbuf, int NB, int nbq) {
  __shared__ f32x2 wl[2][16][17];
  int lane = threadIdx.x;
  int q = lane >> 4, c = lane & 15;       // chain-in-block, unit
  int lq = blockIdx.x / nbq, q4 = blockIdx.x - lq * nbq;
  int l = lq;
  int b = q4 * 4 + q; if (b >= NB) b = NB - 1;   // dup chains: identical writes
  const float* Wg = Whh + (size_t)l * 1024;
  for (int idx = lane; idx < 1024; idx += 64) {  // coalesced one-time fill
    int row = idx >> 4, col = idx & 15;
    int gate = row >> 4, kk = row & 15;
    ((float*)&wl[gate >> 1][kk][col])[gate & 1] = Wg[idx];
  }
  __syncthreads();
  const f32x2* wla = wl[0][c];
  const f32x2* wlb = wl[1][c];
  int sel = (0xE54770 >> l) & 1;                 // per-lstm real/imag selection
  const unsigned short* xs = sel ? xi : xr;
  // A-frag source: lane (q,c) holds x row m = c -> b_local=c>>2, dt=c&3.
  int ba = q4 * 4 + (c >> 2); if (ba >= NB) ba = NB - 1;
  const unsigned short* ap2 = xs + ((size_t)ba * 200 + (c & 3)) * 64 + q * 8;
  // B-frag source: Wih row jt*16 + c, channels q*8+e (jt stride 1024 ushorts)
  const unsigned short* wrow = wbf + l * 4096 + c * 64 + q * 8;
  // bias splats (C-operand of first MFMA of each gate)
  float bv0 = bihh[l * 64 + c], bv1 = bihh[l * 64 + 16 + c];
  float bv2 = bihh[l * 64 + 32 + c], bv3 = bihh[l * 64 + 48 + c];
  f32x4 zb0 = {bv0, bv0, bv0, bv0}, zb1 = {bv1, bv1, bv1, bv1};
  f32x4 zb2 = {bv2, bv2, bv2, bv2}, zb3 = {bv3, bv3, bv3, bv3};
  float* hp = hbuf + ((size_t)l * NB + b) * 3200 + c;
  float h = 0.f, cs = 0.f;
  int tcur = 0;
// packed FMA, h-half broadcast via op_sel. ACC/W are f32x2 (VGPR pairs),
// HP is the f32x2 holding {h_even, h_odd}. src1 = HP.
#define PKL(ACC, W, HP) { f32x2 w_ = (W); \
  asm("v_pk_fma_f32 %0, %1, %2, %0 op_sel:[0,0,0] op_sel_hi:[1,0,1]" \
      : "+v"(ACC) : "v"(w_), "v"(HP)); }
#define PKH(ACC, W, HP) { f32x2 w_ = (W); \
  asm("v_pk_fma_f32 %0, %1, %2, %0 op_sel:[0,1,0] op_sel_hi:[1,1,1]" \
      : "+v"(ACC) : "v"(w_), "v"(HP)); }
#define MG1(DST, OFS, ZB, A0v, A1v) { \
  bf16x8 w0_ = *(const bf16x8*)(wrow + OFS); \
  bf16x8 w1_ = *(const bf16x8*)(wrow + OFS + 32); \
  f32x4 t_ = __builtin_amdgcn_mfma_f32_16x16x32_bf16(A0v, w0_, ZB, 0, 0, 0); \
  DST = __builtin_amdgcn_mfma_f32_16x16x32_bf16(A1v, w1_, t_, 0, 0, 0); }
#define MGROUP(D0, D1, D2, D3, A0v, A1v) \
  MG1(D0, 0, zb0, A0v, A1v) MG1(D1, 1024, zb1, A0v, A1v) \
  MG1(D2, 2048, zb2, A0v, A1v) MG1(D3, 3072, zb3, A0v, A1v)
#define HV(i) dpp_bcast<0x150 + i>(h)
#define LSTEP2(AC0, AC1, AC2, AC3, FLD) { \
  f32x2 ph0, ph1, ph2, ph3, ph4, ph5, ph6, ph7; \
  ph0.x = HV(0);  ph0.y = HV(1);  ph1.x = HV(2);  ph1.y = HV(3);  \
  ph2.x = HV(4);  ph2.y = HV(5);  ph3.x = HV(6);  ph3.y = HV(7);  \
  ph4.x = HV(8);  ph4.y = HV(9);  ph5.x = HV(10); ph5.y = HV(11); \
  ph6.x = HV(12); ph6.y = HV(13); ph7.x = HV(14); ph7.y = HV(15); \
  f32x2 pA, pB, qA, qB; \
  pA.x = AC0.FLD; pA.y = AC1.FLD; qA.x = AC2.FLD; qA.y = AC3.FLD; \
  pB.x = 0.f; pB.y = 0.f; qB.x = 0.f; qB.y = 0.f; \
  PKL(pA, wla[0],  ph0) PKH(pB, wla[1],  ph0) \
  PKL(qA, wlb[0],  ph0) PKH(qB, wlb[1],  ph0) \
  PKL(pA, wla[2],  ph1) PKH(pB, wla[3],  ph1) \
  PKL(qA, wlb[2],  ph1) PKH(qB, wlb[3],  ph1) \
  PKL(pA, wla[4],  ph2) PKH(pB, wla[5],  ph2) \
  PKL(qA, wlb[4],  ph2) PKH(qB, wlb[5],  ph2) \
  PKL(pA, wla[6],  ph3) PKH(pB, wla[7],  ph3) \
  PKL(qA, wlb[6],  ph3) PKH(qB, wlb[7],  ph3) \
  PKL(pA, wla[8],  ph4) PKH(pB, wla[9],  ph4) \
  PKL(qA, wlb[8],  ph4) PKH(qB, wlb[9],  ph4) \
  PKL(pA, wla[10], ph5) PKH(pB, wla[11], ph5) \
  PKL(qA, wlb[10], ph5) PKH(qB, wlb[11], ph5) \
  PKL(pA, wla[12], ph6) PKH(pB, wla[13], ph6) \
  PKL(qA, wlb[12], ph6) PKH(qB, wlb[13], ph6) \
  PKL(pA, wla[14], ph7) PKH(pB, wla[15], ph7) \
  PKL(qA, wlb[14], ph7) PKH(qB, wlb[15], ph7) \
  float ai_ = pA.x + pB.x, af_ = pA.y + pB.y; \
  float ag_ = qA.x + qB.x, ao_ = qA.y + qB.y; \
  float ig_ = sigf(ai_), fg_ = sigf(af_); \
  float gg_ = tanh_(ag_), og_ = sigf(ao_); \
  cs = fg_ * cs + ig_ * gg_; \
  h = og_ * tanh_(cs); \
  hp[tcur * 16] = h; ++tcur; }
  // prologue: group 0 pre-acts; prefetch A of group 1
  bf16x8 a0 = *(const bf16x8*)(ap2), a1 = *(const bf16x8*)(ap2 + 32);
  f32x4 c0, c1, c2, c3, n0, n1, n2, n3;
  MGROUP(c0, c1, c2, c3, a0, a1);
  ap2 += 256;
  a0 = *(const bf16x8*)(ap2); a1 = *(const bf16x8*)(ap2 + 32);
  for (int g = 0; g < 50; ++g) {
    LSTEP2(c0, c1, c2, c3, x)
    LSTEP2(c0, c1, c2, c3, y)
    MGROUP(n0, n1, n2, n3, a0, a1);      // pre-acts for group g+1
    if (g < 48) ap2 += 256;              // A of group g+2 (clamped at end)
    a0 = *(const bf16x8*)(ap2); a1 = *(const bf16x8*)(ap2 + 32);
    LSTEP2(c0, c1, c2, c3, z)
    LSTEP2(c0, c1, c2, c3, w)
    c0 = n0; c1 = n1; c2 = n2; c3 = n3;
  }
#undef LSTEP2
#undef HV
#undef MGROUP
#undef MG1
#undef PKL
#undef PKH
}

// ---------------- kernel C: attention per (branch, bl). Multiplicative causal
// mask before softmax: masked s get weight exp(0); handled via suffix-V init.
__global__ __launch_bounds__(256) void k_attn(const float* __restrict__ hbuf,
                                              float* __restrict__ att, int NB) {
  __shared__ float Q[200][17];
  __shared__ float K[200][16];
  __shared__ float V[200][16];
  __shared__ float Vs[200][17];
  int bid = blockIdx.x;                 // 8 br x NB
  int br = bid / NB, b = bid - br * NB;
  int tid = threadIdx.x;
  const float* qg = hbuf + ((size_t)(br * 3 + 0) * NB + b) * 3200;
  const float* kg = hbuf + ((size_t)(br * 3 + 1) * NB + b) * 3200;
  const float* vg = hbuf + ((size_t)(br * 3 + 2) * NB + b) * 3200;
  for (int i = 0; i < 4; ++i) {         // 200 rows x 4 f4 each of Q,K,V
    int idx = tid + i * 256;
    if (idx < 800) {
      int t = idx >> 2, q = idx & 3;
      float4 a = *(const float4*)(qg + t * 16 + q * 4);
      Q[t][q*4+0] = a.x; Q[t][q*4+1] = a.y; Q[t][q*4+2] = a.z; Q[t][q*4+3] = a.w;
      *(float4*)&K[t][q * 4] = *(const float4*)(kg + t * 16 + q * 4);
      *(float4*)&V[t][q * 4] = *(const float4*)(vg + t * 16 + q * 4);
    }
  }
  __syncthreads();
  if (tid < 16) {                       // suffix sums of V
    float acc = 0.f;
    Vs[199][tid] = 0.f;
    for (int t = 198; t >= 0; --t) { acc += V[t + 1][tid]; Vs[t][tid] = acc; }
  }
  __syncthreads();
  if (tid < 200) {
    int t = tid;
    float q0[16], va[16];
    #pragma unroll
    for (int k = 0; k < 16; ++k) q0[k] = Q[t][k] * 0.25f;   // fold /sqrt(16)
    #pragma unroll
    for (int k = 0; k < 16; ++k) va[k] = Vs[t][k];          // masked: weight exp(0)=1
    float S = (float)(199 - t);
    for (int s = 0; s <= t; ++s) {
      float e = 0.f;
      #pragma unroll
      for (int k = 0; k < 16; ++k) e += q0[k] * K[s][k];
      float wgt = __expf(e);
      S += wgt;
      #pragma unroll
      for (int k = 0; k < 16; ++k) va[k] += wgt * V[s][k];
    }
    float inv = __fdividef(1.f, S);
    float* dst = att + (((size_t)br * NB + b) * 200 + t) * 16;
    #pragma unroll
    for (int q = 0; q < 4; ++q) {
      float4 v; v.x = va[q*4+0]*inv; v.y = va[q*4+1]*inv;
      v.z = va[q*4+2]*inv; v.w = va[q*4+3]*inv;
      *(float4*)(dst + q * 4) = v;
    }
  }
}

// ---------------- kernel D: combine branches + LN2 + complex linear + LN3 +
// PReLU + residual, with LDS transpose for coalesced [N,C,F,T,2] IO.
__global__ __launch_bounds__(256) void k_out(const float* __restrict__ att,
    const float* __restrict__ in,
    const float* __restrict__ ln2w, const float* __restrict__ ln2b,
    const float* __restrict__ lrw, const float* __restrict__ lrb,
    const float* __restrict__ liw, const float* __restrict__ lib,
    const float* __restrict__ ln3w, const float* __restrict__ ln3b,
    const float* __restrict__ pa, float* __restrict__ out, int b0, int NB) {
  __shared__ float as_[8][40][17];
  __shared__ float ys[40][2][17];
  __shared__ float zs[64][81];
  int bid = blockIdx.x;                 // NB nf-local x 5 tiles of 40 t
  int nfl = bid / 5, tile = bid - nfl * 5;
  int nf = b0 + nfl;
  int t0 = tile * 40;
  int n = nf / 100, f = nf - n * 100;
  int tid = threadIdx.x;
  for (int i = 0; i < 5; ++i) {         // att: 8 br x 40 t x 4 f4
    int idx = tid + i * 256;
    int br = idx / 160, r = idx - br * 160;
    int t = r >> 2, q = r & 3;
    float4 v = *(const float4*)(att + (((size_t)br * NB + nfl) * 200 + t0 + t) * 16 + q * 4);
    as_[br][t][q*4+0] = v.x; as_[br][t][q*4+1] = v.y;
    as_[br][t][q*4+2] = v.z; as_[br][t][q*4+3] = v.w;
  }
  __syncthreads();
  if (tid < 80) {                       // combine + LN2 per (t,ri)
    int t = tid >> 1, ri = tid & 1;
    float vv[16]; float s = 0.f, ss = 0.f;
    #pragma unroll
    for (int k = 0; k < 16; ++k) {
      float v;
      if (ri == 0) v = as_[0][t][k] - as_[1][t][k] - as_[2][t][k] - as_[3][t][k];
      else         v = as_[4][t][k] + as_[5][t][k] + as_[6][t][k] - as_[7][t][k];
      vv[k] = v; s += v; ss += v * v;
    }
    float mean = s * 0.0625f;
    float var  = ss * 0.0625f - mean * mean;
    float rstd = rsqrtf(var + 1e-5f);
    #pragma unroll
    for (int k = 0; k < 16; ++k)
      ys[t][ri][k] = (vv[k] - mean) * rstd * ln2w[k] + ln2b[k];
  }
  __syncthreads();
  // complex linear 16->64 + LN3 over c (wave = 64 lanes = c) + PReLU
  int wv = tid >> 6, cc = tid & 63;
  float lr[16], li[16];
  #pragma unroll
  for (int q = 0; q < 4; ++q) {
    float4 v = *(const float4*)(lrw + cc * 16 + q * 4);
    lr[q*4+0] = v.x; lr[q*4+1] = v.y; lr[q*4+2] = v.z; lr[q*4+3] = v.w;
    float4 u = *(const float4*)(liw + cc * 16 + q * 4);
    li[q*4+0] = u.x; li[q*4+1] = u.y; li[q*4+2] = u.z; li[q*4+3] = u.w;
  }
  float brc = lrb[cc], bic = lib[cc];
  float w3 = ln3w[cc], b3 = ln3b[cc];
  float aP = pa[0];
  for (int tt = wv; tt < 40; tt += 4) {
    float zr = brc - bic, zi = brc + bic;
    #pragma unroll
    for (int k = 0; k < 16; ++k) {
      float yr = ys[tt][0][k], yi = ys[tt][1][k];
      zr += yr * lr[k] - yi * li[k];
      zi += yi * lr[k] + yr * li[k];
    }
    float s1 = zr, s2 = zr * zr, s3 = zi, s4 = zi * zi;
    #pragma unroll
    for (int m = 1; m < 64; m <<= 1) {
      s1 += __shfl_xor(s1, m, 64);
      s2 += __shfl_xor(s2, m, 64);
      s3 += __shfl_xor(s3, m, 64);
      s4 += __shfl_xor(s4, m, 64);
    }
    float mr = s1 * 0.015625f, vr = s2 * 0.015625f - mr * mr;
    float mi = s3 * 0.015625f, vi = s4 * 0.015625f - mi * mi;
    float r1 = (zr - mr) * rsqrtf(vr + 1e-5f) * w3 + b3;
    float r2 = (zi - mi) * rsqrtf(vi + 1e-5f) * w3 + b3;
    r1 = r1 >= 0.f ? r1 : aP * r1;
    r2 = r2 >= 0.f ? r2 : aP * r2;
    zs[cc][tt * 2 + 0] = r1;
    zs[cc][tt * 2 + 1] = r2;
  }
  __syncthreads();
  for (int i = 0; i < 5; ++i) {         // residual + coalesced write
    int idx = tid + i * 256;            // 64 c x 20 f4
    int c = idx / 20, q = idx - c * 20;
    size_t gaddr = (size_t)((n * 64 + c) * 100 + f) * 400 + t0 * 2 + q * 4;
    float4 v = *(const float4*)(in + gaddr);
    float4 z;
    z.x = zs[c][q*4+0] + v.x; z.y = zs[c][q*4+1] + v.y;
    z.z = zs[c][q*4+2] + v.z; z.w = zs[c][q*4+3] + v.w;
    *(float4*)(out + gaddr) = z;
  }
}

extern "C" void kernel_launch(void* const* d_in, const int* in_sizes, int n_in,
                              void* d_out, int out_size, void* d_ws, size_t ws_size,
                              hipStream_t stream) {
  (void)in_sizes; (void)n_in; (void)out_size;
  const float* inputs = (const float*)d_in[0];
  const float* Wih  = (const float*)d_in[1];
  const float* Whh  = (const float*)d_in[2];
  const float* bih  = (const float*)d_in[3];
  const float* bhh  = (const float*)d_in[4];
  const float* ln1w = (const float*)d_in[5];
  const float* ln1b = (const float*)d_in[6];
  const float* ln2w = (const float*)d_in[7];
  const float* ln2b = (const float*)d_in[8];
  const float* lrw  = (const float*)d_in[9];
  const float* lrb  = (const float*)d_in[10];
  const float* liw  = (const float*)d_in[11];
  const float* lib  = (const float*)d_in[12];
  const float* ln3w = (const float*)d_in[13];
  const float* ln3b = (const float*)d_in[14];
  const float* pa   = (const float*)d_in[15];
  float* out = (float*)d_out;
  char* ws = (char*)d_ws;

  // pick largest chunk NB (400,200,100,50,25) whose buffers fit ws_size
  // per-b: xr+xi 51200 + h 307200 + att 102400 = 460800 B (xg is gone)
  int NB = 400;
  while (NB > 25 && 204800ull + (size_t)NB * 460800ull > ws_size) NB /= 2;
  int nch = 400 / NB;

  float* bihh = (float*)(ws + 0);                        // 6 KB
  unsigned short* wbf = (unsigned short*)(ws + 8192);    // 192 KB bf16 Wih
  size_t o_xr = 204800;
  size_t o_xi = o_xr + (size_t)NB * 25600;
  size_t o_h  = o_xi + (size_t)NB * 25600;
  size_t o_at = o_h  + (size_t)NB * 307200;
  unsigned short* xr = (unsigned short*)(ws + o_xr);
  unsigned short* xi = (unsigned short*)(ws + o_xi);
  float* hbuf = (float*)(ws + o_h);
  float* att  = (float*)(ws + o_at);

  k_prep<<<384, 256, 0, stream>>>(bih, bhh, Wih, bihh, wbf);
  int nbq = (NB + 3) >> 2;              // 4-chain groups per l
  for (int ch = 0; ch < nch; ++ch) {
    int b0 = ch * NB;
    k_ln1 <<<NB * 4,   256, 0, stream>>>(inputs, ln1w, ln1b, xr, xi, b0);
    k_lstm<<<24 * nbq,  64, 0, stream>>>(xr, xi, wbf, bihh, Whh, hbuf, NB, nbq);
    k_attn<<<8 * NB,   256, 0, stream>>>(hbuf, att, NB);
    k_out <<<NB * 5,   256, 0, stream>>>(att, inputs, ln2w, ln2b, lrw, lrb,
                                         liw, lib, ln3w, ln3b, pa, out, b0, NB);
  }
}